// Round 1
// baseline (193.989 us; speedup 1.0000x reference)
//
#include <hip/hip_runtime.h>

#define NROWS 262144
#define NE 5
#define TM 64
#define TILES (NROWS / TM)   // 4096

typedef __attribute__((ext_vector_type(8))) short short8;
typedef __attribute__((ext_vector_type(4))) float f32x4;

__device__ __forceinline__ unsigned short f2bf(float x) {
  unsigned u = __float_as_uint(x);
  u += 0x7FFF + ((u >> 16) & 1);   // round-to-nearest-even
  return (unsigned short)(u >> 16);
}
__device__ __forceinline__ float bf2f(unsigned short h) {
  return __uint_as_float(((unsigned)h) << 16);
}

// ---------------- kernel 1: convert W1,W2 to transposed bf16 -----------------
// Wt[e][j][k] = W[e][k][j]  (so MFMA B-fragments are contiguous 16B reads)
__global__ __launch_bounds__(256) void convw(const float* __restrict__ W1,
                                             const float* __restrict__ W2,
                                             unsigned short* __restrict__ Wt1,
                                             unsigned short* __restrict__ Wt2) {
  int idx = blockIdx.x * 256 + threadIdx.x;       // 0 .. 163839
  int which = idx / 81920;                        // 0 -> W1, 1 -> W2
  int rem = idx % 81920;
  int e = rem / 16384;
  int jk = rem % 16384;
  int j = jk / 128;
  int k = jk % 128;
  const float* W = which ? W2 : W1;
  unsigned short* Wt = which ? Wt2 : Wt1;
  Wt[e * 16384 + j * 128 + k] = f2bf(W[e * 16384 + k * 128 + j]);
}

// ---------------- kernel 2: classify rows into expert buckets ---------------
__global__ __launch_bounds__(256) void classify(const float* __restrict__ x,
                                                int* __restrict__ bucket,
                                                int* __restrict__ cnt) {
  int r = blockIdx.x * 256 + threadIdx.x;         // grid covers exactly NROWS
  float t = x[(size_t)r * 129];
  int e = (t >= 0.2f) + (t >= 0.4f) + (t >= 0.6f) + (t >= 0.8f);
  __shared__ int lc[NE];
  __shared__ int lb[NE];
  if (threadIdx.x < NE) lc[threadIdx.x] = 0;
  __syncthreads();
  int lpos = atomicAdd(&lc[e], 1);
  __syncthreads();
  if (threadIdx.x < NE) lb[threadIdx.x] = atomicAdd(&cnt[threadIdx.x], lc[threadIdx.x]);
  __syncthreads();
  bucket[(size_t)e * NROWS + lb[e] + lpos] = r;
}

// ---------------- kernel 3: per-expert tiled MLP with bf16 MFMA -------------
__global__ __launch_bounds__(256) void mlp(
    const float* __restrict__ x,
    const unsigned short* __restrict__ Wt1, const float* __restrict__ tw1, const float* __restrict__ b1,
    const unsigned short* __restrict__ Wt2, const float* __restrict__ tw2, const float* __restrict__ b2,
    const float* __restrict__ W3, const float* __restrict__ tw3, const float* __restrict__ b3,
    const int* __restrict__ bucket, const int* __restrict__ cnt,
    float* __restrict__ out) {
  int e = blockIdx.x / TILES;
  int it = blockIdx.x % TILES;
  int n = cnt[e];
  int i0 = it * TM;
  if (i0 >= n) return;
  int nv = min(TM, n - i0);

  __shared__ unsigned short bufA[TM * 128];   // f tile, later h2 tile (swizzled)
  __shared__ unsigned short bufB[TM * 128];   // h1 tile (swizzled)
  __shared__ float tS[TM];
  __shared__ int rS[TM];

  int tid = threadIdx.x;
  const int* bk = bucket + (size_t)e * NROWS + i0;
  if (tid < TM) {
    int r = bk[min(tid, nv - 1)];
    rS[tid] = r;
    tS[tid] = x[(size_t)r * 129];
  }
  __syncthreads();

  char* pA = (char*)bufA;
  char* pB = (char*)bufB;

  // ---- stage f tile (fp32 -> bf16, swizzled LDS) ----
  for (int q = 0; q < 32; ++q) {
    int g = q * 256 + tid;
    int s = g >> 7;          // row slot (wave-uniform)
    int c = g & 127;         // feature
    float v = x[(size_t)rS[s] * 129 + 1 + c];
    int off = (s * 256 + c * 2) ^ ((s & 7) << 4);
    *(unsigned short*)(pA + off) = f2bf(v);
  }
  __syncthreads();

  int wave = tid >> 6;
  int lane = tid & 63;
  int lr = lane & 15;        // row-in-16 for A, col for B/D
  int lq = lane >> 4;        // k-quad / d-row-quad
  int rowt = wave * 16;      // this wave's 16 rows

  const unsigned short* W1e = Wt1 + e * 16384;
  const unsigned short* W2e = Wt2 + e * 16384;

  short8 a[4];

  // ===== layer 1: h1 = relu(f @ W1 + t*tw1 + b1) =====
#pragma unroll
  for (int ks = 0; ks < 4; ++ks) {
    int row = rowt + lr;
    int off = (row * 256 + ks * 64 + lq * 16) ^ ((row & 7) << 4);
    a[ks] = *(const short8*)(pA + off);
  }
#pragma unroll
  for (int ct = 0; ct < 8; ++ct) {
    f32x4 acc = {0.f, 0.f, 0.f, 0.f};
#pragma unroll
    for (int ks = 0; ks < 4; ++ks) {
      short8 b = *(const short8*)(W1e + (ct * 16 + lr) * 128 + ks * 32 + lq * 8);
      acc = __builtin_amdgcn_mfma_f32_16x16x32_bf16(a[ks], b, acc, 0, 0, 0);
    }
    int col = ct * 16 + lr;
    float twv = tw1[e * 128 + col];
    float bv = b1[e * 128 + col];
#pragma unroll
    for (int r = 0; r < 4; ++r) {
      int row = rowt + lq * 4 + r;
      float v = fmaxf(acc[r] + tS[row] * twv + bv, 0.f);
      int off = (row * 256 + col * 2) ^ ((row & 7) << 4);
      *(unsigned short*)(pB + off) = f2bf(v);
    }
  }
  __syncthreads();

  // ===== layer 2: h2 = relu(h1 @ W2 + t*tw2 + b2) =====
#pragma unroll
  for (int ks = 0; ks < 4; ++ks) {
    int row = rowt + lr;
    int off = (row * 256 + ks * 64 + lq * 16) ^ ((row & 7) << 4);
    a[ks] = *(const short8*)(pB + off);
  }
#pragma unroll
  for (int ct = 0; ct < 8; ++ct) {
    f32x4 acc = {0.f, 0.f, 0.f, 0.f};
#pragma unroll
    for (int ks = 0; ks < 4; ++ks) {
      short8 b = *(const short8*)(W2e + (ct * 16 + lr) * 128 + ks * 32 + lq * 8);
      acc = __builtin_amdgcn_mfma_f32_16x16x32_bf16(a[ks], b, acc, 0, 0, 0);
    }
    int col = ct * 16 + lr;
    float twv = tw2[e * 128 + col];
    float bv = b2[e * 128 + col];
#pragma unroll
    for (int r = 0; r < 4; ++r) {
      int row = rowt + lq * 4 + r;
      float v = fmaxf(acc[r] + tS[row] * twv + bv, 0.f);
      int off = (row * 256 + col * 2) ^ ((row & 7) << 4);
      *(unsigned short*)(pA + off) = f2bf(v);
    }
  }
  __syncthreads();

  // ===== layer 3: o = h2 @ W3 + t*tw3 + b3 (128-dot, 4 lanes/row) =====
  {
    int s = tid >> 2;
    int part = tid & 3;
    const float* W3e = W3 + e * 128;
    float sum = 0.f;
#pragma unroll
    for (int q = 0; q < 4; ++q) {
      int off = (s * 256 + part * 64 + q * 16) ^ ((s & 7) << 4);
      short8 hv = *(const short8*)(pA + off);
#pragma unroll
      for (int j = 0; j < 8; ++j) {
        sum += bf2f((unsigned short)hv[j]) * W3e[part * 32 + q * 8 + j];
      }
    }
    sum += __shfl_xor(sum, 1);
    sum += __shfl_xor(sum, 2);
    if (part == 0 && s < nv) {
      out[rS[s]] = sum + tS[s] * tw3[e] + b3[e];
    }
  }
}

extern "C" void kernel_launch(void* const* d_in, const int* in_sizes, int n_in,
                              void* d_out, int out_size, void* d_ws, size_t ws_size,
                              hipStream_t stream) {
  const float* x   = (const float*)d_in[0];
  const float* W1  = (const float*)d_in[1];
  const float* tw1 = (const float*)d_in[2];
  const float* b1  = (const float*)d_in[3];
  const float* W2  = (const float*)d_in[4];
  const float* tw2 = (const float*)d_in[5];
  const float* b2  = (const float*)d_in[6];
  const float* W3  = (const float*)d_in[7];
  const float* tw3 = (const float*)d_in[8];
  const float* b3  = (const float*)d_in[9];
  float* out = (float*)d_out;

  char* ws = (char*)d_ws;
  int* cnt = (int*)ws;                                   // 5 ints (256B reserved)
  int* bucket = (int*)(ws + 256);                        // 5*NROWS ints = 5 MB
  unsigned short* Wt1 = (unsigned short*)(ws + 256 + (size_t)NE * NROWS * 4);
  unsigned short* Wt2 = Wt1 + NE * 16384;                // +160KB each

  hipMemsetAsync(cnt, 0, NE * sizeof(int), stream);
  convw<<<640, 256, 0, stream>>>(W1, W2, Wt1, Wt2);
  classify<<<NROWS / 256, 256, 0, stream>>>(x, bucket, cnt);
  mlp<<<NE * TILES, 256, 0, stream>>>(x, Wt1, tw1, b1, Wt2, tw2, b2, W3, tw3, b3,
                                      bucket, cnt, out);
}

// Round 2
// 167.151 us; speedup vs baseline: 1.1606x; 1.1606x over previous
//
#include <hip/hip_runtime.h>

#define NROWS 262144
#define NE 5
#define TM 64
#define TILES (NROWS / TM)   // 4096

typedef __attribute__((ext_vector_type(8))) short short8;
typedef __attribute__((ext_vector_type(4))) float f32x4;

__device__ __forceinline__ unsigned short f2bf(float x) {
  unsigned u = __float_as_uint(x);
  u += 0x7FFF + ((u >> 16) & 1);   // round-to-nearest-even
  return (unsigned short)(u >> 16);
}

// ---------------- kernel 1: convert W1,W2 to transposed bf16 -----------------
// Wt[e][j][k] = W[e][k][j]  (MFMA B-fragments become contiguous 16B reads)
__global__ __launch_bounds__(256) void convw(const float* __restrict__ W1,
                                             const float* __restrict__ W2,
                                             unsigned short* __restrict__ Wt1,
                                             unsigned short* __restrict__ Wt2) {
  int idx = blockIdx.x * 256 + threadIdx.x;       // 0 .. 163839
  int which = idx / 81920;
  int rem = idx % 81920;
  int e = rem / 16384;
  int jk = rem % 16384;
  int j = jk / 128;
  int k = jk % 128;
  const float* W = which ? W2 : W1;
  unsigned short* Wt = which ? Wt2 : Wt1;
  Wt[e * 16384 + j * 128 + k] = f2bf(W[e * 16384 + k * 128 + j]);
}

// ---------------- kernel 2: classify rows into expert buckets ---------------
__global__ __launch_bounds__(256) void classify(const float* __restrict__ x,
                                                int* __restrict__ bucket,
                                                int* __restrict__ cnt) {
  int r = blockIdx.x * 256 + threadIdx.x;
  float t = x[(size_t)r * 129];
  int e = (t >= 0.2f) + (t >= 0.4f) + (t >= 0.6f) + (t >= 0.8f);
  __shared__ int lc[NE];
  __shared__ int lb[NE];
  if (threadIdx.x < NE) lc[threadIdx.x] = 0;
  __syncthreads();
  int lpos = atomicAdd(&lc[e], 1);
  __syncthreads();
  if (threadIdx.x < NE) lb[threadIdx.x] = atomicAdd(&cnt[threadIdx.x], lc[threadIdx.x]);
  __syncthreads();
  bucket[(size_t)e * NROWS + lb[e] + lpos] = r;
}

// ------- kernel 3: per-expert MLP, fully wave-independent, no barriers ------
__global__ __launch_bounds__(256, 4) void mlp(
    const float* __restrict__ x,
    const unsigned short* __restrict__ Wt1, const float* __restrict__ tw1, const float* __restrict__ b1,
    const unsigned short* __restrict__ Wt2, const float* __restrict__ tw2, const float* __restrict__ b2,
    const float* __restrict__ W3, const float* __restrict__ tw3, const float* __restrict__ b3,
    const int* __restrict__ bucket, const int* __restrict__ cnt,
    float* __restrict__ out) {
  int e = blockIdx.x / TILES;
  int it = blockIdx.x % TILES;
  int n = cnt[e];
  int i0 = it * TM;
  if (i0 >= n) return;

  __shared__ unsigned short hbuf[4][16 * 128];   // per-wave h1 transpose (swizzled)

  int tid  = threadIdx.x;
  int wave = tid >> 6;
  int lane = tid & 63;
  int lr = lane & 15;        // A-row within wave's 16 / D-col within ct
  int lq = lane >> 4;        // k-quad / D-row-quad
  int rbase = i0 + wave * 16;

  const int* bk = bucket + (size_t)e * NROWS;

  // this lane's A-row index (clamped for tail tiles)
  int r = bk[min(rbase + lr, n - 1)];

  // D-rows this lane owns (rows lq*4+rr): indices + t values, loaded per-lane
  int   r4[4];
  float t4[4];
#pragma unroll
  for (int rr = 0; rr < 4; ++rr)
    r4[rr] = bk[min(rbase + lq * 4 + rr, n - 1)];
#pragma unroll
  for (int rr = 0; rr < 4; ++rr)
    t4[rr] = x[(size_t)r4[rr] * 129];

  // ---- A fragments of f, loaded DIRECTLY from global (32 loads in flight) ----
  const float* fp = x + (size_t)r * 129 + 1 + lq * 8;
  float fv[32];
#pragma unroll
  for (int ks = 0; ks < 4; ++ks)
#pragma unroll
    for (int j = 0; j < 8; ++j)
      fv[ks * 8 + j] = fp[ks * 32 + j];

  short8 a[4];
#pragma unroll
  for (int ks = 0; ks < 4; ++ks)
#pragma unroll
    for (int j = 0; j < 8; ++j)
      a[ks][j] = (short)f2bf(fv[ks * 8 + j]);

  const unsigned short* W1e = Wt1 + e * 16384;
  char* hp = (char*)hbuf[wave];

  // ===== layer 1: h1 = relu(f @ W1 + t*tw1 + b1) -> per-wave LDS (swizzled) =====
#pragma unroll
  for (int ct = 0; ct < 8; ++ct) {
    f32x4 acc = {0.f, 0.f, 0.f, 0.f};
#pragma unroll
    for (int ks = 0; ks < 4; ++ks) {
      short8 b = *(const short8*)(W1e + (ct * 16 + lr) * 128 + ks * 32 + lq * 8);
      acc = __builtin_amdgcn_mfma_f32_16x16x32_bf16(a[ks], b, acc, 0, 0, 0);
    }
    int col = ct * 16 + lr;
    float twv = tw1[e * 128 + col];
    float bv  = b1[e * 128 + col];
#pragma unroll
    for (int rr = 0; rr < 4; ++rr) {
      int row = lq * 4 + rr;
      float v = fmaxf(acc[rr] + t4[rr] * twv + bv, 0.f);
      int off = (row * 256 + col * 2) ^ ((row & 7) << 4);
      *(unsigned short*)(hp + off) = f2bf(v);
    }
  }

  // wave-local LDS fence: writes above, transposed reads below (rule 18)
  asm volatile("s_waitcnt lgkmcnt(0)" ::: "memory");
  __builtin_amdgcn_sched_barrier(0);

#pragma unroll
  for (int ks = 0; ks < 4; ++ks) {
    int off = (lr * 256 + ks * 64 + lq * 16) ^ ((lr & 7) << 4);
    a[ks] = *(const short8*)(hp + off);
  }

  // ===== layer 2 + fused layer 3: o += relu(h1@W2 + t*tw2 + b2) * W3 =====
  const unsigned short* W2e = Wt2 + e * 16384;
  const float* W3e = W3 + e * 128;
  float o[4] = {0.f, 0.f, 0.f, 0.f};
#pragma unroll
  for (int ct = 0; ct < 8; ++ct) {
    f32x4 acc = {0.f, 0.f, 0.f, 0.f};
#pragma unroll
    for (int ks = 0; ks < 4; ++ks) {
      short8 b = *(const short8*)(W2e + (ct * 16 + lr) * 128 + ks * 32 + lq * 8);
      acc = __builtin_amdgcn_mfma_f32_16x16x32_bf16(a[ks], b, acc, 0, 0, 0);
    }
    int col = ct * 16 + lr;
    float twv = tw2[e * 128 + col];
    float bv  = b2[e * 128 + col];
    float w3v = W3e[col];
#pragma unroll
    for (int rr = 0; rr < 4; ++rr) {
      float v = fmaxf(acc[rr] + t4[rr] * twv + bv, 0.f);
      o[rr] += v * w3v;
    }
  }

  // reduce over the 16 cols held across lanes lr=0..15 (xor stays in-group)
#pragma unroll
  for (int rr = 0; rr < 4; ++rr) {
    float s = o[rr];
    s += __shfl_xor(s, 1);
    s += __shfl_xor(s, 2);
    s += __shfl_xor(s, 4);
    s += __shfl_xor(s, 8);
    o[rr] = s;
  }

  if (lr == 0) {
    float tw3v = tw3[e];
    float b3v  = b3[e];
#pragma unroll
    for (int rr = 0; rr < 4; ++rr) {
      if (rbase + lq * 4 + rr < n)
        out[r4[rr]] = o[rr] + t4[rr] * tw3v + b3v;
    }
  }
}

extern "C" void kernel_launch(void* const* d_in, const int* in_sizes, int n_in,
                              void* d_out, int out_size, void* d_ws, size_t ws_size,
                              hipStream_t stream) {
  const float* x   = (const float*)d_in[0];
  const float* W1  = (const float*)d_in[1];
  const float* tw1 = (const float*)d_in[2];
  const float* b1  = (const float*)d_in[3];
  const float* W2  = (const float*)d_in[4];
  const float* tw2 = (const float*)d_in[5];
  const float* b2  = (const float*)d_in[6];
  const float* W3  = (const float*)d_in[7];
  const float* tw3 = (const float*)d_in[8];
  const float* b3  = (const float*)d_in[9];
  float* out = (float*)d_out;

  char* ws = (char*)d_ws;
  int* cnt = (int*)ws;                                   // 5 ints (256B reserved)
  int* bucket = (int*)(ws + 256);                        // 5*NROWS ints = 5 MB
  unsigned short* Wt1 = (unsigned short*)(ws + 256 + (size_t)NE * NROWS * 4);
  unsigned short* Wt2 = Wt1 + NE * 16384;

  hipMemsetAsync(cnt, 0, NE * sizeof(int), stream);
  convw<<<640, 256, 0, stream>>>(W1, W2, Wt1, Wt2);
  classify<<<NROWS / 256, 256, 0, stream>>>(x, bucket, cnt);
  mlp<<<NE * TILES, 256, 0, stream>>>(x, Wt1, tw1, b1, Wt2, tw2, b2, W3, tw3, b3,
                                      bucket, cnt, out);
}

// Round 3
// 119.904 us; speedup vs baseline: 1.6179x; 1.3940x over previous
//
#include <hip/hip_runtime.h>

#define NROWS 262144
#define NE 5
#define TM 128                   // rows per block = 4 waves x 32
#define TILES (NROWS / TM)       // 2048

typedef __attribute__((ext_vector_type(8))) short short8;
typedef __attribute__((ext_vector_type(4))) float f32x4;

__device__ __forceinline__ unsigned short f2bf(float x) {
  unsigned u = __float_as_uint(x);
  u += 0x7FFF + ((u >> 16) & 1);   // round-to-nearest-even
  return (unsigned short)(u >> 16);
}

// ---------------- kernel 1: convert W1,W2 to transposed bf16 -----------------
// Wt[e][j][k] = W[e][k][j]  (MFMA B-fragments become contiguous 16B reads)
__global__ __launch_bounds__(256) void convw(const float* __restrict__ W1,
                                             const float* __restrict__ W2,
                                             unsigned short* __restrict__ Wt1,
                                             unsigned short* __restrict__ Wt2) {
  int idx = blockIdx.x * 256 + threadIdx.x;       // 0 .. 163839
  int which = idx / 81920;
  int rem = idx % 81920;
  int e = rem / 16384;
  int jk = rem % 16384;
  int j = jk / 128;
  int k = jk % 128;
  const float* W = which ? W2 : W1;
  unsigned short* Wt = which ? Wt2 : Wt1;
  Wt[e * 16384 + j * 128 + k] = f2bf(W[e * 16384 + k * 128 + j]);
}

// ---------------- kernel 2: classify rows into expert buckets ---------------
__global__ __launch_bounds__(256) void classify(const float* __restrict__ x,
                                                int* __restrict__ bucket,
                                                int* __restrict__ cnt) {
  int r = blockIdx.x * 256 + threadIdx.x;
  float t = x[(size_t)r * 129];
  int e = (t >= 0.2f) + (t >= 0.4f) + (t >= 0.6f) + (t >= 0.8f);
  __shared__ int lc[NE];
  __shared__ int lb[NE];
  if (threadIdx.x < NE) lc[threadIdx.x] = 0;
  __syncthreads();
  int lpos = atomicAdd(&lc[e], 1);
  __syncthreads();
  if (threadIdx.x < NE) lb[threadIdx.x] = atomicAdd(&cnt[threadIdx.x], lc[threadIdx.x]);
  __syncthreads();
  bucket[(size_t)e * NROWS + lb[e] + lpos] = r;
}

// ---- kernel 3: per-expert MLP, 32 rows/wave, coalesced staging, no barriers -
__global__ __launch_bounds__(256, 4) void mlp(
    const float* __restrict__ x,
    const unsigned short* __restrict__ Wt1, const float* __restrict__ tw1, const float* __restrict__ b1,
    const unsigned short* __restrict__ Wt2, const float* __restrict__ tw2, const float* __restrict__ b2,
    const float* __restrict__ W3, const float* __restrict__ tw3, const float* __restrict__ b3,
    const int* __restrict__ bucket, const int* __restrict__ cnt,
    float* __restrict__ out) {
  int e = blockIdx.x / TILES;
  int it = blockIdx.x % TILES;
  int n = cnt[e];
  int i0 = it * TM;
  if (i0 >= n) return;

  __shared__ unsigned short hbuf[4][32 * 128];   // 8 KB per wave, swizzled

  int tid  = threadIdx.x;
  int wave = tid >> 6;
  int lane = tid & 63;
  int lr = lane & 15;        // A-row within 16-group / D-col within ct
  int lq = lane >> 4;        // k-quad / D-row-quad
  int rbase = i0 + wave * 32;

  const int* bk = bucket + (size_t)e * NROWS;

  // 32 bucketed row ids for this wave (lanes 0..31; dup on 32..63), coalesced
  int rI = bk[min(rbase + (lane & 31), n - 1)];
  float tv = x[(size_t)rI * 129];

  char* hp = (char*)hbuf[wave];

  // ---- stage f tile: per step, 64 lanes read 64 CONSECUTIVE floats of 1 row -
#pragma unroll
  for (int s = 0; s < 64; ++s) {
    int row = s >> 1;
    int col = ((s & 1) << 6) | lane;
    int rrow = __shfl(rI, row);
    float v = x[(size_t)rrow * 129 + 1 + col];
    int off = (row * 256 + col * 2) ^ ((row & 7) << 4);
    *(unsigned short*)(hp + off) = f2bf(v);
  }

  // t values and output row ids for the D-rows this lane owns, via shuffle
  float t0[4], t1[4];
  int ro0[4], ro1[4];
#pragma unroll
  for (int rr = 0; rr < 4; ++rr) {
    t0[rr] = __shfl(tv, lq * 4 + rr);
    t1[rr] = __shfl(tv, 16 + lq * 4 + rr);
    ro0[rr] = __shfl(rI, lq * 4 + rr);
    ro1[rr] = __shfl(rI, 16 + lq * 4 + rr);
  }

  // wave-local LDS fence (rule 18)
  asm volatile("s_waitcnt lgkmcnt(0)" ::: "memory");
  __builtin_amdgcn_sched_barrier(0);

  short8 a0[4], a1[4];
#pragma unroll
  for (int ks = 0; ks < 4; ++ks) {
    int off0 = (lr * 256 + ks * 64 + lq * 16) ^ ((lr & 7) << 4);
    int off1 = ((16 + lr) * 256 + ks * 64 + lq * 16) ^ ((lr & 7) << 4);
    a0[ks] = *(const short8*)(hp + off0);
    a1[ks] = *(const short8*)(hp + off1);
  }

  const unsigned short* W1e = Wt1 + e * 16384;

  // ===== layer 1: h1 = relu(f @ W1 + t*tw1 + b1) -> same LDS (f is dead) ====
  // (all a-frags are consumed by ct=0's MFMAs, so reads complete before writes)
#pragma unroll
  for (int ct = 0; ct < 8; ++ct) {
    f32x4 acc0 = {0.f, 0.f, 0.f, 0.f};
    f32x4 acc1 = {0.f, 0.f, 0.f, 0.f};
#pragma unroll
    for (int ks = 0; ks < 4; ++ks) {
      short8 b = *(const short8*)(W1e + (ct * 16 + lr) * 128 + ks * 32 + lq * 8);
      acc0 = __builtin_amdgcn_mfma_f32_16x16x32_bf16(a0[ks], b, acc0, 0, 0, 0);
      acc1 = __builtin_amdgcn_mfma_f32_16x16x32_bf16(a1[ks], b, acc1, 0, 0, 0);
    }
    int col = ct * 16 + lr;
    float twv = tw1[e * 128 + col];
    float bv  = b1[e * 128 + col];
#pragma unroll
    for (int rr = 0; rr < 4; ++rr) {
      int row0 = lq * 4 + rr;
      int row1 = row0 + 16;
      float v0 = fmaxf(acc0[rr] + t0[rr] * twv + bv, 0.f);
      float v1 = fmaxf(acc1[rr] + t1[rr] * twv + bv, 0.f);
      *(unsigned short*)(hp + ((row0 * 256 + col * 2) ^ ((row0 & 7) << 4))) = f2bf(v0);
      *(unsigned short*)(hp + ((row1 * 256 + col * 2) ^ ((row1 & 7) << 4))) = f2bf(v1);
    }
  }

  asm volatile("s_waitcnt lgkmcnt(0)" ::: "memory");
  __builtin_amdgcn_sched_barrier(0);

#pragma unroll
  for (int ks = 0; ks < 4; ++ks) {
    int off0 = (lr * 256 + ks * 64 + lq * 16) ^ ((lr & 7) << 4);
    int off1 = ((16 + lr) * 256 + ks * 64 + lq * 16) ^ ((lr & 7) << 4);
    a0[ks] = *(const short8*)(hp + off0);
    a1[ks] = *(const short8*)(hp + off1);
  }

  // ===== layer 2 + fused layer 3: o += relu(h1@W2 + t*tw2 + b2) * W3 ========
  const unsigned short* W2e = Wt2 + e * 16384;
  const float* W3e = W3 + e * 128;
  float o0[4] = {0.f, 0.f, 0.f, 0.f};
  float o1[4] = {0.f, 0.f, 0.f, 0.f};
#pragma unroll
  for (int ct = 0; ct < 8; ++ct) {
    f32x4 acc0 = {0.f, 0.f, 0.f, 0.f};
    f32x4 acc1 = {0.f, 0.f, 0.f, 0.f};
#pragma unroll
    for (int ks = 0; ks < 4; ++ks) {
      short8 b = *(const short8*)(W2e + (ct * 16 + lr) * 128 + ks * 32 + lq * 8);
      acc0 = __builtin_amdgcn_mfma_f32_16x16x32_bf16(a0[ks], b, acc0, 0, 0, 0);
      acc1 = __builtin_amdgcn_mfma_f32_16x16x32_bf16(a1[ks], b, acc1, 0, 0, 0);
    }
    int col = ct * 16 + lr;
    float twv = tw2[e * 128 + col];
    float bv  = b2[e * 128 + col];
    float w3v = W3e[col];
#pragma unroll
    for (int rr = 0; rr < 4; ++rr) {
      float v0 = fmaxf(acc0[rr] + t0[rr] * twv + bv, 0.f);
      float v1 = fmaxf(acc1[rr] + t1[rr] * twv + bv, 0.f);
      o0[rr] += v0 * w3v;
      o1[rr] += v1 * w3v;
    }
  }

  // reduce over the 16 cols held across lanes lr=0..15 (xor stays in-group)
#pragma unroll
  for (int rr = 0; rr < 4; ++rr) {
    float s0 = o0[rr], s1 = o1[rr];
    s0 += __shfl_xor(s0, 1);  s1 += __shfl_xor(s1, 1);
    s0 += __shfl_xor(s0, 2);  s1 += __shfl_xor(s1, 2);
    s0 += __shfl_xor(s0, 4);  s1 += __shfl_xor(s1, 4);
    s0 += __shfl_xor(s0, 8);  s1 += __shfl_xor(s1, 8);
    o0[rr] = s0;  o1[rr] = s1;
  }

  if (lr == 0) {
    float tw3v = tw3[e];
    float b3v  = b3[e];
#pragma unroll
    for (int rr = 0; rr < 4; ++rr) {
      if (rbase + lq * 4 + rr < n)
        out[ro0[rr]] = o0[rr] + t0[rr] * tw3v + b3v;
      if (rbase + 16 + lq * 4 + rr < n)
        out[ro1[rr]] = o1[rr] + t1[rr] * tw3v + b3v;
    }
  }
}

extern "C" void kernel_launch(void* const* d_in, const int* in_sizes, int n_in,
                              void* d_out, int out_size, void* d_ws, size_t ws_size,
                              hipStream_t stream) {
  const float* x   = (const float*)d_in[0];
  const float* W1  = (const float*)d_in[1];
  const float* tw1 = (const float*)d_in[2];
  const float* b1  = (const float*)d_in[3];
  const float* W2  = (const float*)d_in[4];
  const float* tw2 = (const float*)d_in[5];
  const float* b2  = (const float*)d_in[6];
  const float* W3  = (const float*)d_in[7];
  const float* tw3 = (const float*)d_in[8];
  const float* b3  = (const float*)d_in[9];
  float* out = (float*)d_out;

  char* ws = (char*)d_ws;
  int* cnt = (int*)ws;                                   // 5 ints (256B reserved)
  int* bucket = (int*)(ws + 256);                        // 5*NROWS ints = 5 MB
  unsigned short* Wt1 = (unsigned short*)(ws + 256 + (size_t)NE * NROWS * 4);
  unsigned short* Wt2 = Wt1 + NE * 16384;

  hipMemsetAsync(cnt, 0, NE * sizeof(int), stream);
  convw<<<640, 256, 0, stream>>>(W1, W2, Wt1, Wt2);
  classify<<<NROWS / 256, 256, 0, stream>>>(x, bucket, cnt);
  mlp<<<NE * TILES, 256, 0, stream>>>(x, Wt1, tw1, b1, Wt2, tw2, b2, W3, tw3, b3,
                                      bucket, cnt, out);
}